// Round 3
// baseline (450.299 us; speedup 1.0000x reference)
//
#include <hip/hip_runtime.h>

typedef __bf16 bf16x8 __attribute__((ext_vector_type(8)));
typedef float  f32x4  __attribute__((ext_vector_type(4)));
typedef unsigned short u16;
typedef unsigned short us4 __attribute__((ext_vector_type(4)));

__device__ __forceinline__ u16 f2bf(float f) {
  __bf16 h = (__bf16)f;
  return __builtin_bit_cast(u16, h);
}

__device__ __forceinline__ void gload16(const void* g, void* l) {
  __builtin_amdgcn_global_load_lds(
      (const __attribute__((address_space(1))) unsigned int*)(g),
      (__attribute__((address_space(3))) unsigned int*)(l), 16, 0, 0);
}

__device__ __forceinline__ void barrier_lgkm() {
  asm volatile("s_waitcnt lgkmcnt(0)" ::: "memory");
  __builtin_amdgcn_s_barrier();
  asm volatile("" ::: "memory");
}
template <int N> __device__ __forceinline__ void vmwait() {
  asm volatile("s_waitcnt vmcnt(%0)" :: "n"(N) : "memory");
}

// ---------------- GroupNorm: pass 1 (partial sums) ----------------
__global__ void gn_partial(const float* __restrict__ x, float* __restrict__ part) {
  const int chunk = blockIdx.x, g = blockIdx.y, b = blockIdx.z;
  const int tid = threadIdx.x;
  float s = 0.f, ss = 0.f;
  const float* xb = x + ((size_t)(b * 4096 + chunk * 512)) * 512 + g * 16;
  for (int i = tid; i < 2048; i += 256) {
    const int sp = i >> 2, c4 = (i & 3) << 2;
    const float4 v = *(const float4*)(xb + (size_t)sp * 512 + c4);
    s  += v.x + v.y + v.z + v.w;
    ss += v.x * v.x + v.y * v.y + v.z * v.z + v.w * v.w;
  }
  for (int m = 32; m; m >>= 1) { s += __shfl_xor(s, m); ss += __shfl_xor(ss, m); }
  __shared__ float red[8];
  const int w = tid >> 6;
  if ((tid & 63) == 0) { red[w * 2] = s; red[w * 2 + 1] = ss; }
  __syncthreads();
  if (tid == 0) {
    float S = 0.f, SS = 0.f;
    for (int i = 0; i < 4; ++i) { S += red[2 * i]; SS += red[2 * i + 1]; }
    const int idx = ((b * 32 + g) * 8 + chunk) * 2;
    part[idx] = S; part[idx + 1] = SS;
  }
}

// ---------------- GroupNorm: pass 2 (finalize) ----------------
__global__ void gn_finalize(const float* __restrict__ part, float* __restrict__ stats) {
  const int t = threadIdx.x;  // 128 = 4*32
  if (t < 128) {
    float S = 0.f, SS = 0.f;
    for (int i = 0; i < 8; ++i) { S += part[(t * 8 + i) * 2]; SS += part[(t * 8 + i) * 2 + 1]; }
    const float mean = S * (1.0f / 65536.0f);
    const float var  = SS * (1.0f / 65536.0f) - mean * mean;
    stats[t * 2] = mean;
    stats[t * 2 + 1] = rsqrtf(var + 1e-6f);
  }
}

// ---------------- GroupNorm: pass 3 (normalize + cast bf16) ----------------
__global__ void gn_apply(const float* __restrict__ x, const float* __restrict__ gamma,
                         const float* __restrict__ beta, const float* __restrict__ stats,
                         u16* __restrict__ h) {
  const size_t i = (size_t)blockIdx.x * 256 + threadIdx.x;
  const size_t e = i * 4;
  const int c = (int)(e & 511);
  const int b = (int)(e >> 21);
  const int g = c >> 4;
  const float mean = stats[(b * 32 + g) * 2];
  const float rstd = stats[(b * 32 + g) * 2 + 1];
  const float4 xv = *(const float4*)(x + e);
  const float4 gv = *(const float4*)(gamma + c);
  const float4 bv = *(const float4*)(beta + c);
  us4 hv;
  hv.x = f2bf((xv.x - mean) * rstd * gv.x + bv.x);
  hv.y = f2bf((xv.y - mean) * rstd * gv.y + bv.y);
  hv.z = f2bf((xv.z - mean) * rstd * gv.z + bv.z);
  hv.w = f2bf((xv.w - mean) * rstd * gv.w + bv.w);
  *(us4*)(h + e) = hv;
}

// ---------------- weight transpose + cast ----------------
__global__ void wcast_t(const float* __restrict__ w, u16* __restrict__ wT) {
  const int idx = blockIdx.x * 256 + threadIdx.x;
  const int n = idx >> 9, k = idx & 511;
  wT[idx] = f2bf(w[k * 512 + n]);
}

#define GEMM_STAGE(buf, t)                                                       \
  {                                                                              \
    const int k0 = (t) * 32;                                                     \
    _Pragma("unroll")                                                            \
    for (int i = 0; i < 2; ++i) {                                                \
      const int cid = tid + i * 256;                                             \
      const int row = cid >> 2, cb = cid & 3;                                    \
      const int sc = (cb ^ (row & 3)) << 3;                                      \
      gload16(A + (size_t)(brow + row) * 512 + k0 + sc, &lA[buf][cid << 3]);     \
      gload16(Bt + (size_t)(bcol0 + row) * 512 + k0 + sc, &lB[buf][cid << 3]);   \
    }                                                                            \
  }

#define GEMM_MAIN                                                                \
  const f32x4 zero4 = {0.f, 0.f, 0.f, 0.f};                                      \
  f32x4 acc[4][4];                                                               \
  _Pragma("unroll") for (int a_ = 0; a_ < 4; ++a_)                               \
  _Pragma("unroll") for (int b_ = 0; b_ < 4; ++b_) acc[a_][b_] = zero4;          \
  GEMM_STAGE(0, 0);                                                              \
  asm volatile("s_waitcnt vmcnt(0)" ::: "memory");                               \
  __syncthreads();                                                               \
  int buf = 0;                                                                   \
  for (int t = 0; t < 16; ++t) {                                                 \
    if (t < 15) GEMM_STAGE(buf ^ 1, t + 1);                                      \
    bf16x8 af[4], bfv[4];                                                        \
    _Pragma("unroll") for (int f = 0; f < 4; ++f) {                              \
      const int ra = wr * 64 + f * 16 + l15;                                     \
      af[f] = *(const bf16x8*)(&lA[buf][(ra << 5) + ((lq ^ (ra & 3)) << 3)]);    \
      const int rb = wc * 64 + f * 16 + l15;                                     \
      bfv[f] = *(const bf16x8*)(&lB[buf][(rb << 5) + ((lq ^ (rb & 3)) << 3)]);   \
    }                                                                            \
    _Pragma("unroll") for (int fa = 0; fa < 4; ++fa)                             \
    _Pragma("unroll") for (int fb = 0; fb < 4; ++fb)                             \
      acc[fa][fb] = __builtin_amdgcn_mfma_f32_16x16x32_bf16(af[fa], bfv[fb],     \
                                                            acc[fa][fb], 0, 0, 0);\
    asm volatile("s_waitcnt vmcnt(0)" ::: "memory");                             \
    __syncthreads();                                                             \
    buf ^= 1;                                                                    \
  }

// ---------------- o-projection GEMM: f32 out, +bias +residual ----------------
__global__ __launch_bounds__(256)
void gemm_oproj(const u16* __restrict__ A, const u16* __restrict__ Bt,
                const float* __restrict__ bias, const float* __restrict__ resid,
                float* __restrict__ Cout) {
  const int tid = threadIdx.x;
  const int wid = tid >> 6, l = tid & 63;
  const int wr = wid >> 1, wc = wid & 1;
  const int l15 = l & 15, lq = l >> 4;
  const int brow = blockIdx.x * 128, bcol0 = blockIdx.y * 128;
  __shared__ u16 lA[2][4096];
  __shared__ u16 lB[2][4096];
  GEMM_MAIN
#pragma unroll
  for (int fa = 0; fa < 4; ++fa)
#pragma unroll
    for (int fb = 0; fb < 4; ++fb) {
      const int col = bcol0 + wc * 64 + fb * 16 + l15;
      const float bv = bias[col];
#pragma unroll
      for (int i = 0; i < 4; ++i) {
        const int row = brow + wr * 64 + fa * 16 + lq * 4 + i;
        const size_t idx = (size_t)row * 512 + col;
        Cout[idx] = acc[fa][fb][i] + bv + resid[idx];
      }
    }
}

// ---------------- fused QKV GEMM: grid (128, 12) ----------------
__global__ __launch_bounds__(256)
void gemm_qkv(const u16* __restrict__ A, const u16* __restrict__ wT,
              const float* __restrict__ bq, const float* __restrict__ bk,
              const float* __restrict__ bv_, u16* __restrict__ q,
              u16* __restrict__ k, u16* __restrict__ v8, float qs) {
  const int tid = threadIdx.x;
  const int wid = tid >> 6, l = tid & 63;
  const int wr = wid >> 1, wc = wid & 1;
  const int l15 = l & 15, lq = l >> 4;
  const int which = blockIdx.y >> 2;
  const int brow = blockIdx.x * 128, bcol0 = (blockIdx.y & 3) * 128;
  const u16* Bt = wT + which * 262144;
  const float* bias = (which == 0) ? bq : ((which == 1) ? bk : bv_);
  __shared__ u16 lA[2][4096];
  __shared__ u16 lB[2][4096];
  GEMM_MAIN
#pragma unroll
  for (int fa = 0; fa < 4; ++fa)
#pragma unroll
    for (int fb = 0; fb < 4; ++fb) {
      const int col = bcol0 + wc * 64 + fb * 16 + l15;
      const float bb_ = bias[col];
#pragma unroll
      for (int i = 0; i < 4; ++i) {
        const int row = brow + wr * 64 + fa * 16 + lq * 4 + i;
        const float v = acc[fa][fb][i] + bb_;
        if (which == 0) {
          q[(size_t)row * 512 + col] = f2bf(v * qs);
        } else if (which == 1) {
          k[(size_t)row * 512 + col] = f2bf(v);
        } else {
          const int bb = row >> 12, n = row & 4095;
          // V8 layout with nb-XOR bank swizzle baked in (chunk index ^= block&3)
          v8[((size_t)(bb * 512 + (n >> 3))) * 4096 +
             (size_t)((col ^ ((n >> 3) & 3)) << 3) + (n & 7)] = f2bf(v);
        }
      }
    }
}

// ---------------- flash attention: BQ=64, BKV=64, Mw=32, 8 waves -------------
// grid (64 qblocks, 4 batches), block 512. 1 WG/CU, LDS 158 KB.
__global__ __launch_bounds__(512, 2)
void attn_kernel(const u16* __restrict__ Q, const u16* __restrict__ K,
                 const u16* __restrict__ V8, u16* __restrict__ Oo) {
  const int b = blockIdx.y, qb = blockIdx.x;
  const int tid = threadIdx.x;
  const int wid = tid >> 6, l = tid & 63;
  const int r = wid & 1;    // q-row group: 32 rows
  const int cg = wid >> 1;  // col group: 16 S-cols / 128 O-cols
  const int l15 = l & 15, lq = l >> 4;

  __shared__ u16 Kl[32768];        // 64 KB: K tile [64][512], chunk-XOR swizzled
  __shared__ u16 Vl[32768];        // 64 KB: V tile, blocked [8][512][8] + baked swz
  __shared__ float Sb[64 * 68];    // 17 KB scores
  __shared__ u16 Pb[64 * 72];      // 9 KB probabilities
  __shared__ float mrow[64], lrow[64], arow[64];

  const u16* Kb = K + (size_t)b * 4096 * 512;
  const u16* Vb = V8 + (size_t)b * 4096 * 512;

#define STAGEK(tt)                                                     \
  {                                                                    \
    const u16* ks = Kb + (size_t)(tt) * 32768;                         \
    _Pragma("unroll") for (int i = 0; i < 8; ++i) {                    \
      const int cid = tid + i * 512;                                   \
      const int ob = cid << 4;                                         \
      const int n_ = ob >> 10;                                         \
      const int cb = (ob & 1023) ^ ((n_ & 7) << 4);                    \
      gload16(ks + (size_t)n_ * 512 + (cb >> 1), (char*)Kl + ob);      \
    }                                                                  \
  }
#define STAGEV(tt)                                                     \
  {                                                                    \
    const u16* vs = Vb + (size_t)(tt) * 32768;                         \
    _Pragma("unroll") for (int i = 0; i < 8; ++i) {                    \
      const int cid = tid + i * 512;                                   \
      gload16(vs + (cid << 3), (char*)Vl + (cid << 4));                \
    }                                                                  \
  }

  STAGEK(0);
  STAGEV(0);

  // Q fragments in registers: rows r*32..+32, full depth 512 (128 VGPRs)
  bf16x8 qf[2][16];
#pragma unroll
  for (int t2 = 0; t2 < 2; ++t2) {
    const u16* qp = Q + ((size_t)(b * 4096 + qb * 64 + r * 32 + t2 * 16 + l15)) * 512 + lq * 8;
#pragma unroll
    for (int kk = 0; kk < 16; ++kk) qf[t2][kk] = *(const bf16x8*)(qp + kk * 32);
  }
  const f32x4 zero4 = {0.f, 0.f, 0.f, 0.f};
  f32x4 o[2][8];
#pragma unroll
  for (int t2 = 0; t2 < 2; ++t2)
#pragma unroll
    for (int f = 0; f < 8; ++f) o[t2][f] = zero4;

  if (tid < 64) { mrow[tid] = -__builtin_inff(); lrow[tid] = 0.f; arow[tid] = 1.f; }

  for (int t = 0; t < 64; ++t) {
    vmwait<8>();        // K[t] landed (V[t] may still fly)
    barrier_lgkm();     // #1: K ready

    // ---- S = Q K^T : this wave rows r*32..+32, cols cg*16..+16 ----
    f32x4 sacc0 = zero4, sacc1 = zero4;
    {
      const int n = cg * 16 + l15;
      const int swz = (n & 7) << 4;
      const char* kb = (const char*)Kl + n * 1024;
#pragma unroll
      for (int kk = 0; kk < 16; ++kk) {
        const bf16x8 bfr = *(const bf16x8*)(kb + ((kk * 64 + (lq << 4)) ^ swz));
        sacc0 = __builtin_amdgcn_mfma_f32_16x16x32_bf16(qf[0][kk], bfr, sacc0, 0, 0, 0);
        sacc1 = __builtin_amdgcn_mfma_f32_16x16x32_bf16(qf[1][kk], bfr, sacc1, 0, 0, 0);
      }
    }
    {
      const int col = cg * 16 + l15;
      const int rb = r * 32 + lq * 4;
#pragma unroll
      for (int i = 0; i < 4; ++i) {
        Sb[(rb + i) * 68 + col] = sacc0[i];
        Sb[(rb + 16 + i) * 68 + col] = sacc1[i];
      }
    }
    barrier_lgkm();     // #2: Sb ready, Kl free
    STAGEK((t + 1) & 63);

    // ---- online softmax with defer-max (THR=8), 8 threads/row ----
    {
      const int row = tid >> 3, i8 = tid & 7;
      const float* sp = Sb + row * 68 + i8 * 8;
      const f32x4 sv0 = *(const f32x4*)(sp);
      const f32x4 sv1 = *(const f32x4*)(sp + 4);
      float tmax = fmaxf(fmaxf(fmaxf(sv0[0], sv0[1]), fmaxf(sv0[2], sv0[3])),
                         fmaxf(fmaxf(sv1[0], sv1[1]), fmaxf(sv1[2], sv1[3])));
#pragma unroll
      for (int m = 1; m < 8; m <<= 1) tmax = fmaxf(tmax, __shfl_xor(tmax, m, 8));
      const float mo = mrow[row];
      const bool need = tmax > mo + 8.0f;
      const float mn = need ? tmax : mo;
      const float al = need ? __expf(mo - mn) : 1.0f;
      float p[8];
      p[0] = __expf(sv0[0] - mn); p[1] = __expf(sv0[1] - mn);
      p[2] = __expf(sv0[2] - mn); p[3] = __expf(sv0[3] - mn);
      p[4] = __expf(sv1[0] - mn); p[5] = __expf(sv1[1] - mn);
      p[6] = __expf(sv1[2] - mn); p[7] = __expf(sv1[3] - mn);
      float ps = ((p[0] + p[1]) + (p[2] + p[3])) + ((p[4] + p[5]) + (p[6] + p[7]));
#pragma unroll
      for (int m = 1; m < 8; m <<= 1) ps += __shfl_xor(ps, m, 8);
      bf16x8 pb;
#pragma unroll
      for (int j = 0; j < 8; ++j) pb[j] = (__bf16)p[j];
      *(bf16x8*)(Pb + row * 72 + i8 * 8) = pb;
      if (i8 == 0) {
        lrow[row] = lrow[row] * al + ps;
        mrow[row] = mn;
        arow[row] = al;
      }
    }
    vmwait<8>();        // V[t] landed (K[t+1] may still fly)
    barrier_lgkm();     // #3: Pb/stats ready, V ready

    // ---- rescale O (rare) ----
    {
      const int rb = r * 32 + lq * 4;
      float av[2][4];
      bool anyr = false;
#pragma unroll
      for (int t2 = 0; t2 < 2; ++t2)
#pragma unroll
        for (int i = 0; i < 4; ++i) {
          av[t2][i] = arow[rb + t2 * 16 + i];
          anyr |= (av[t2][i] != 1.0f);
        }
      if (anyr) {
#pragma unroll
        for (int t2 = 0; t2 < 2; ++t2)
#pragma unroll
          for (int f = 0; f < 8; ++f) {
            o[t2][f][0] *= av[t2][0]; o[t2][f][1] *= av[t2][1];
            o[t2][f][2] *= av[t2][2]; o[t2][f][3] *= av[t2][3];
          }
      }
    }
    // ---- O += P @ V ----
    {
      bf16x8 pa[2][2];
#pragma unroll
      for (int t2 = 0; t2 < 2; ++t2)
#pragma unroll
        for (int s = 0; s < 2; ++s)
          pa[t2][s] = *(const bf16x8*)((const char*)Pb +
                        (r * 32 + t2 * 16 + l15) * 144 + s * 64 + (lq << 4));
      const char* vb2 = (const char*)Vl;
#pragma unroll
      for (int f = 0; f < 8; ++f) {
        const int cc = cg * 128 + f * 16 + l15;
#pragma unroll
        for (int s = 0; s < 2; ++s) {
          const bf16x8 vf = *(const bf16x8*)(vb2 + ((s * 4 + lq) << 13) + ((cc ^ lq) << 4));
          o[0][f] = __builtin_amdgcn_mfma_f32_16x16x32_bf16(pa[0][s], vf, o[0][f], 0, 0, 0);
          o[1][f] = __builtin_amdgcn_mfma_f32_16x16x32_bf16(pa[1][s], vf, o[1][f], 0, 0, 0);
        }
      }
    }
    barrier_lgkm();     // #4: Vl free
    STAGEV((t + 1) & 63);
  }
#undef STAGEK
#undef STAGEV

  // ---- epilogue: O /= l, cast bf16, store ----
  {
    const int rb = r * 32 + lq * 4;
    float li[2][4];
#pragma unroll
    for (int t2 = 0; t2 < 2; ++t2)
#pragma unroll
      for (int i = 0; i < 4; ++i) li[t2][i] = 1.0f / lrow[rb + t2 * 16 + i];
    u16* ob = Oo + ((size_t)(b * 4096 + qb * 64)) * 512;
#pragma unroll
    for (int t2 = 0; t2 < 2; ++t2)
#pragma unroll
      for (int f = 0; f < 8; ++f) {
        const int col = cg * 128 + f * 16 + l15;
#pragma unroll
        for (int i = 0; i < 4; ++i)
          ob[(size_t)(rb + t2 * 16 + i) * 512 + col] = f2bf(o[t2][f][i] * li[t2][i]);
      }
  }
}

extern "C" void kernel_launch(void* const* d_in, const int* in_sizes, int n_in,
                              void* d_out, int out_size, void* d_ws, size_t ws_size,
                              hipStream_t stream) {
  const float* x     = (const float*)d_in[0];
  const float* gamma = (const float*)d_in[1];
  const float* beta  = (const float*)d_in[2];
  const float* wq    = (const float*)d_in[3];
  const float* bq    = (const float*)d_in[4];
  const float* wk    = (const float*)d_in[5];
  const float* bk    = (const float*)d_in[6];
  const float* wv    = (const float*)d_in[7];
  const float* bv    = (const float*)d_in[8];
  const float* wo    = (const float*)d_in[9];
  const float* bo    = (const float*)d_in[10];
  float* out = (float*)d_out;

  char* ws = (char*)d_ws;
  const size_t SZ = (size_t)16384 * 512;
  u16* h    = (u16*)(ws);                 // 16 MB
  u16* q    = (u16*)(ws + SZ * 2);        // 16 MB (pre-scaled by C^-0.5)
  u16* k    = (u16*)(ws + SZ * 4);        // 16 MB
  u16* v8   = (u16*)(ws + SZ * 6);        // 16 MB, [B][N/8][C^(blk&3)][8]
  u16* aout = (u16*)(ws + SZ * 8);        // 16 MB
  u16* wT   = (u16*)(ws + SZ * 10);       // 4 x 512KB
  float* part  = (float*)(ws + SZ * 10 + 4 * 262144 * 2);
  float* stats = part + 2048;

  gn_partial<<<dim3(8, 32, 4), 256, 0, stream>>>(x, part);
  gn_finalize<<<1, 128, 0, stream>>>(part, stats);
  gn_apply<<<8192, 256, 0, stream>>>(x, gamma, beta, stats, h);

  wcast_t<<<1024, 256, 0, stream>>>(wq, wT);
  wcast_t<<<1024, 256, 0, stream>>>(wk, wT + 262144);
  wcast_t<<<1024, 256, 0, stream>>>(wv, wT + 2 * 262144);
  wcast_t<<<1024, 256, 0, stream>>>(wo, wT + 3 * 262144);

  const float qs = 0.044194173824159216f;  // 512^-0.5
  gemm_qkv<<<dim3(128, 12), 256, 0, stream>>>(h, wT, bq, bk, bv, q, k, v8, qs);

  attn_kernel<<<dim3(64, 4), 512, 0, stream>>>(q, k, v8, aout);

  gemm_oproj<<<dim3(128, 4), 256, 0, stream>>>(aout, wT + 3 * 262144, bo, x, out);
}

// Round 4
// 355.364 us; speedup vs baseline: 1.2671x; 1.2671x over previous
//
#include <hip/hip_runtime.h>

typedef __bf16 bf16x8 __attribute__((ext_vector_type(8)));
typedef float  f32x4  __attribute__((ext_vector_type(4)));
typedef unsigned short u16;
typedef unsigned short us4 __attribute__((ext_vector_type(4)));

__device__ __forceinline__ u16 f2bf(float f) {
  __bf16 h = (__bf16)f;
  return __builtin_bit_cast(u16, h);
}

__device__ __forceinline__ void gload16(const void* g, void* l) {
  __builtin_amdgcn_global_load_lds(
      (const __attribute__((address_space(1))) unsigned int*)(g),
      (__attribute__((address_space(3))) unsigned int*)(l), 16, 0, 0);
}

__device__ __forceinline__ void barrier_lgkm() {
  asm volatile("s_waitcnt lgkmcnt(0)" ::: "memory");
  __builtin_amdgcn_s_barrier();
  asm volatile("" ::: "memory");
}
template <int N> __device__ __forceinline__ void vmwait() {
  asm volatile("s_waitcnt vmcnt(%0)" :: "n"(N) : "memory");
}

// ---------------- GroupNorm: pass 1 (partial sums) ----------------
__global__ void gn_partial(const float* __restrict__ x, float* __restrict__ part) {
  const int chunk = blockIdx.x, g = blockIdx.y, b = blockIdx.z;
  const int tid = threadIdx.x;
  float s = 0.f, ss = 0.f;
  const float* xb = x + ((size_t)(b * 4096 + chunk * 512)) * 512 + g * 16;
  for (int i = tid; i < 2048; i += 256) {
    const int sp = i >> 2, c4 = (i & 3) << 2;
    const float4 v = *(const float4*)(xb + (size_t)sp * 512 + c4);
    s  += v.x + v.y + v.z + v.w;
    ss += v.x * v.x + v.y * v.y + v.z * v.z + v.w * v.w;
  }
  for (int m = 32; m; m >>= 1) { s += __shfl_xor(s, m); ss += __shfl_xor(ss, m); }
  __shared__ float red[8];
  const int w = tid >> 6;
  if ((tid & 63) == 0) { red[w * 2] = s; red[w * 2 + 1] = ss; }
  __syncthreads();
  if (tid == 0) {
    float S = 0.f, SS = 0.f;
    for (int i = 0; i < 4; ++i) { S += red[2 * i]; SS += red[2 * i + 1]; }
    const int idx = ((b * 32 + g) * 8 + chunk) * 2;
    part[idx] = S; part[idx + 1] = SS;
  }
}

// ---------------- GroupNorm: pass 2 (finalize) ----------------
__global__ void gn_finalize(const float* __restrict__ part, float* __restrict__ stats) {
  const int t = threadIdx.x;  // 128 = 4*32
  if (t < 128) {
    float S = 0.f, SS = 0.f;
    for (int i = 0; i < 8; ++i) { S += part[(t * 8 + i) * 2]; SS += part[(t * 8 + i) * 2 + 1]; }
    const float mean = S * (1.0f / 65536.0f);
    const float var  = SS * (1.0f / 65536.0f) - mean * mean;
    stats[t * 2] = mean;
    stats[t * 2 + 1] = rsqrtf(var + 1e-6f);
  }
}

// ---------------- GroupNorm: pass 3 (normalize + cast bf16) ----------------
__global__ void gn_apply(const float* __restrict__ x, const float* __restrict__ gamma,
                         const float* __restrict__ beta, const float* __restrict__ stats,
                         u16* __restrict__ h) {
  const size_t i = (size_t)blockIdx.x * 256 + threadIdx.x;
  const size_t e = i * 4;
  const int c = (int)(e & 511);
  const int b = (int)(e >> 21);
  const int g = c >> 4;
  const float mean = stats[(b * 32 + g) * 2];
  const float rstd = stats[(b * 32 + g) * 2 + 1];
  const float4 xv = *(const float4*)(x + e);
  const float4 gv = *(const float4*)(gamma + c);
  const float4 bv = *(const float4*)(beta + c);
  us4 hv;
  hv.x = f2bf((xv.x - mean) * rstd * gv.x + bv.x);
  hv.y = f2bf((xv.y - mean) * rstd * gv.y + bv.y);
  hv.z = f2bf((xv.z - mean) * rstd * gv.z + bv.z);
  hv.w = f2bf((xv.w - mean) * rstd * gv.w + bv.w);
  *(us4*)(h + e) = hv;
}

// ---------------- fused weight transpose + cast (all 4 weights) ----------------
__global__ void wcast_t4(const float* __restrict__ wq, const float* __restrict__ wk,
                         const float* __restrict__ wv, const float* __restrict__ wo,
                         u16* __restrict__ wT) {
  const int idx = blockIdx.x * 256 + threadIdx.x;  // 0..1048575
  const int which = idx >> 18;
  const int rr = idx & 262143;
  const float* w = (which == 0) ? wq : (which == 1) ? wk : (which == 2) ? wv : wo;
  const int n = rr >> 9, k = rr & 511;
  wT[idx] = f2bf(w[k * 512 + n]);
}

#define GEMM_STAGE(buf, t)                                                       \
  {                                                                              \
    const int k0 = (t) * 32;                                                     \
    _Pragma("unroll")                                                            \
    for (int i = 0; i < 2; ++i) {                                                \
      const int cid = tid + i * 256;                                             \
      const int row = cid >> 2, cb = cid & 3;                                    \
      const int sc = (cb ^ (row & 3)) << 3;                                      \
      gload16(A + (size_t)(brow + row) * 512 + k0 + sc, &lA[buf][cid << 3]);     \
      gload16(Bt + (size_t)(bcol0 + row) * 512 + k0 + sc, &lB[buf][cid << 3]);   \
    }                                                                            \
  }

#define GEMM_MAIN                                                                \
  const f32x4 zero4 = {0.f, 0.f, 0.f, 0.f};                                      \
  f32x4 acc[4][4];                                                               \
  _Pragma("unroll") for (int a_ = 0; a_ < 4; ++a_)                               \
  _Pragma("unroll") for (int b_ = 0; b_ < 4; ++b_) acc[a_][b_] = zero4;          \
  GEMM_STAGE(0, 0);                                                              \
  asm volatile("s_waitcnt vmcnt(0)" ::: "memory");                               \
  __syncthreads();                                                               \
  int buf = 0;                                                                   \
  for (int t = 0; t < 16; ++t) {                                                 \
    if (t < 15) GEMM_STAGE(buf ^ 1, t + 1);                                      \
    bf16x8 af[4], bfv[4];                                                        \
    _Pragma("unroll") for (int f = 0; f < 4; ++f) {                              \
      const int ra = wr * 64 + f * 16 + l15;                                     \
      af[f] = *(const bf16x8*)(&lA[buf][(ra << 5) + ((lq ^ (ra & 3)) << 3)]);    \
      const int rb = wc * 64 + f * 16 + l15;                                     \
      bfv[f] = *(const bf16x8*)(&lB[buf][(rb << 5) + ((lq ^ (rb & 3)) << 3)]);   \
    }                                                                            \
    _Pragma("unroll") for (int fa = 0; fa < 4; ++fa)                             \
    _Pragma("unroll") for (int fb = 0; fb < 4; ++fb)                             \
      acc[fa][fb] = __builtin_amdgcn_mfma_f32_16x16x32_bf16(af[fa], bfv[fb],     \
                                                            acc[fa][fb], 0, 0, 0);\
    asm volatile("s_waitcnt vmcnt(0)" ::: "memory");                             \
    __syncthreads();                                                             \
    buf ^= 1;                                                                    \
  }

// ---------------- o-projection GEMM: f32 out, +bias +residual ----------------
__global__ __launch_bounds__(256)
void gemm_oproj(const u16* __restrict__ A, const u16* __restrict__ Bt,
                const float* __restrict__ bias, const float* __restrict__ resid,
                float* __restrict__ Cout) {
  const int tid = threadIdx.x;
  const int wid = tid >> 6, l = tid & 63;
  const int wr = wid >> 1, wc = wid & 1;
  const int l15 = l & 15, lq = l >> 4;
  const int brow = blockIdx.x * 128, bcol0 = blockIdx.y * 128;
  __shared__ u16 lA[2][4096];
  __shared__ u16 lB[2][4096];
  GEMM_MAIN
#pragma unroll
  for (int fa = 0; fa < 4; ++fa)
#pragma unroll
    for (int fb = 0; fb < 4; ++fb) {
      const int col = bcol0 + wc * 64 + fb * 16 + l15;
      const float bv = bias[col];
#pragma unroll
      for (int i = 0; i < 4; ++i) {
        const int row = brow + wr * 64 + fa * 16 + lq * 4 + i;
        const size_t idx = (size_t)row * 512 + col;
        Cout[idx] = acc[fa][fb][i] + bv + resid[idx];
      }
    }
}

// ---------------- fused QKV GEMM: grid (128, 12) ----------------
__global__ __launch_bounds__(256)
void gemm_qkv(const u16* __restrict__ A, const u16* __restrict__ wT,
              const float* __restrict__ bq, const float* __restrict__ bk,
              const float* __restrict__ bv_, u16* __restrict__ q,
              u16* __restrict__ k, u16* __restrict__ v8, float qs) {
  const int tid = threadIdx.x;
  const int wid = tid >> 6, l = tid & 63;
  const int wr = wid >> 1, wc = wid & 1;
  const int l15 = l & 15, lq = l >> 4;
  const int which = blockIdx.y >> 2;
  const int brow = blockIdx.x * 128, bcol0 = (blockIdx.y & 3) * 128;
  const u16* Bt = wT + which * 262144;
  const float* bias = (which == 0) ? bq : ((which == 1) ? bk : bv_);
  __shared__ u16 lA[2][4096];
  __shared__ u16 lB[2][4096];
  GEMM_MAIN
#pragma unroll
  for (int fa = 0; fa < 4; ++fa)
#pragma unroll
    for (int fb = 0; fb < 4; ++fb) {
      const int col = bcol0 + wc * 64 + fb * 16 + l15;
      const float bb_ = bias[col];
#pragma unroll
      for (int i = 0; i < 4; ++i) {
        const int row = brow + wr * 64 + fa * 16 + lq * 4 + i;
        const float v = acc[fa][fb][i] + bb_;
        if (which == 0) {
          q[(size_t)row * 512 + col] = f2bf(v * qs);
        } else if (which == 1) {
          k[(size_t)row * 512 + col] = f2bf(v);
        } else {
          const int bb = row >> 12, n = row & 4095;
          // V8 layout with nb-XOR bank swizzle baked in (chunk index ^= block&3)
          v8[((size_t)(bb * 512 + (n >> 3))) * 4096 +
             (size_t)((col ^ ((n >> 3) & 3)) << 3) + (n & 7)] = f2bf(v);
        }
      }
    }
}

// ---------------- flash attention: BQ=64, BKV=32, 8 waves, 2-barrier pipeline -
// grid (64 qblocks, 4 batches), block 512. 1 WG/CU, LDS ~148 KB.
// Per iteration t: §1 = QK^T(t) fused with PV(t-1); §2 = softmax(t).
__global__ __launch_bounds__(512)
void attn_kernel(const u16* __restrict__ Q, const u16* __restrict__ K,
                 const u16* __restrict__ V8, u16* __restrict__ Oo) {
  const int b = blockIdx.y, qb = blockIdx.x;
  const int tid = threadIdx.x;
  const int wid = tid >> 6, l = tid & 63;
  const int r = wid & 3;    // q-row group (16 rows)
  const int cg = wid >> 2;  // S kv-col group (16 cols) / O d-group (256 cols)
  const int l15 = l & 15, lq = l >> 4;

  __shared__ u16 Kl[2][16384];     // 2 x 32 KB, K tile [32][512] chunk-XOR swizzled
  __shared__ u16 Vl[2][16384];     // 2 x 32 KB, V tile blocked [4][512][8] + baked swz
  __shared__ float Sb[64 * 36];    // 9 KB scores
  __shared__ u16 Pb[2][64 * 40];   // 2 x 5 KB probabilities
  __shared__ float mrow[64], lrow[64], arow[64];

  const u16* Kb = K + (size_t)b * 4096 * 512;
  const u16* Vb = V8 + (size_t)b * 4096 * 512;

#define STAGEK(tt)                                                     \
  {                                                                    \
    const u16* ks = Kb + (size_t)(tt) * 16384;                         \
    char* kd = (char*)(&Kl[(tt) & 1][0]);                              \
    _Pragma("unroll") for (int i = 0; i < 4; ++i) {                    \
      const int cid = tid + i * 512;                                   \
      const int ob = cid << 4;                                         \
      const int n_ = ob >> 10;                                         \
      const int cb = (ob & 1023) ^ ((n_ & 7) << 4);                    \
      gload16(ks + (size_t)n_ * 512 + (cb >> 1), kd + ob);             \
    }                                                                  \
  }
#define STAGEV(tt)                                                     \
  {                                                                    \
    const u16* vs = Vb + (size_t)(tt) * 16384;                         \
    char* vd = (char*)(&Vl[(tt) & 1][0]);                              \
    _Pragma("unroll") for (int i = 0; i < 4; ++i) {                    \
      const int cid = tid + i * 512;                                   \
      gload16(vs + (cid << 3), vd + (cid << 4));                       \
    }                                                                  \
  }

  STAGEK(0);

  // Q fragments in registers: rows r*16..+16, full depth 512 (64 VGPRs)
  bf16x8 qf[16];
  {
    const u16* qp = Q + ((size_t)(b * 4096 + qb * 64 + r * 16 + l15)) * 512 + lq * 8;
#pragma unroll
    for (int kk = 0; kk < 16; ++kk) qf[kk] = *(const bf16x8*)(qp + kk * 32);
  }
  const f32x4 zero4 = {0.f, 0.f, 0.f, 0.f};
  f32x4 o[16];
#pragma unroll
  for (int f = 0; f < 16; ++f) o[f] = zero4;

  if (tid < 64) { mrow[tid] = -__builtin_inff(); lrow[tid] = 0.f; arow[tid] = 1.f; }

  const int n = cg * 16 + l15;          // kv col within tile
  const int swz = (n & 7) << 4;
  const int rb = r * 16 + lq * 4;

  for (int t = 0; t < 128; ++t) {
    vmwait<0>();       // K[t] and V[t-1] landed (issued a full iteration ago)
    barrier_lgkm();    // A: also publishes Pb[t-1]/arow/stats from §2(t-1)
    const int cur = t & 1, prv = cur ^ 1;
    STAGEK((t + 1) & 127);   // -> Kl[(t+1)&1], free since §1(t-1)
    STAGEV(t);               // -> Vl[t&1],    free since §1(t-1)

    // ---- §1: QK^T(t) fused with PV(t-1) ----
    f32x4 sacc = zero4;
    const char* kb = (const char*)(&Kl[cur][0]) + n * 1024;
    if (t > 0) {
      // rescale O by a(t-1) (rare, defer-max)
      const float a0 = arow[rb], a1 = arow[rb + 1], a2 = arow[rb + 2], a3 = arow[rb + 3];
      if (a0 != 1.f || a1 != 1.f || a2 != 1.f || a3 != 1.f) {
#pragma unroll
        for (int f = 0; f < 16; ++f) {
          o[f][0] *= a0; o[f][1] *= a1; o[f][2] *= a2; o[f][3] *= a3;
        }
      }
      const bf16x8 pa = *(const bf16x8*)((const char*)(&Pb[prv][0]) +
                                         (r * 16 + l15) * 80 + (lq << 4));
      const char* vbase = (const char*)(&Vl[prv][0]) + (lq << 13);
#pragma unroll
      for (int kk = 0; kk < 16; ++kk) {
        const bf16x8 kf = *(const bf16x8*)(kb + ((kk * 64 + (lq << 4)) ^ swz));
        sacc = __builtin_amdgcn_mfma_f32_16x16x32_bf16(qf[kk], kf, sacc, 0, 0, 0);
        const int ci = (cg * 256 + kk * 16 + l15) ^ lq;  // baked bank swizzle
        const bf16x8 vf = *(const bf16x8*)(vbase + (ci << 4));
        o[kk] = __builtin_amdgcn_mfma_f32_16x16x32_bf16(pa, vf, o[kk], 0, 0, 0);
      }
    } else {
#pragma unroll
      for (int kk = 0; kk < 16; ++kk) {
        const bf16x8 kf = *(const bf16x8*)(kb + ((kk * 64 + (lq << 4)) ^ swz));
        sacc = __builtin_amdgcn_mfma_f32_16x16x32_bf16(qf[kk], kf, sacc, 0, 0, 0);
      }
    }
    {
      const int col = cg * 16 + l15;
#pragma unroll
      for (int i = 0; i < 4; ++i) Sb[(rb + i) * 36 + col] = sacc[i];
    }
    barrier_lgkm();    // B: Sb ready; Pb[prv]/Vl[prv] now free

    // ---- §2: online softmax(t) with defer-max (THR=8), 8 threads/row ----
    {
      const int row = tid >> 3, i8 = tid & 7;
      const f32x4 sv = *(const f32x4*)(Sb + row * 36 + i8 * 4);
      float tmax = fmaxf(fmaxf(sv[0], sv[1]), fmaxf(sv[2], sv[3]));
#pragma unroll
      for (int m = 1; m < 8; m <<= 1) tmax = fmaxf(tmax, __shfl_xor(tmax, m, 8));
      const float mo = mrow[row];
      const bool need = tmax > mo + 8.0f;
      const float mn = need ? tmax : mo;
      const float al = need ? __expf(mo - mn) : 1.0f;
      const float p0 = __expf(sv[0] - mn), p1 = __expf(sv[1] - mn);
      const float p2 = __expf(sv[2] - mn), p3 = __expf(sv[3] - mn);
      float ps = p0 + p1 + p2 + p3;
#pragma unroll
      for (int m = 1; m < 8; m <<= 1) ps += __shfl_xor(ps, m, 8);
      u16* pp = &Pb[cur][0] + row * 40 + i8 * 4;
      pp[0] = f2bf(p0); pp[1] = f2bf(p1); pp[2] = f2bf(p2); pp[3] = f2bf(p3);
      if (i8 == 0) {
        lrow[row] = lrow[row] * al + ps;
        mrow[row] = mn;
        arow[row] = al;
      }
    }
  }
#undef STAGEK
#undef STAGEV

  // ---- epilogue: final PV(127), then O /= l, cast bf16, store ----
  vmwait<0>();
  barrier_lgkm();      // publishes Pb[1]/arow/lrow from §2(127)
  {
    const float a0 = arow[rb], a1 = arow[rb + 1], a2 = arow[rb + 2], a3 = arow[rb + 3];
    if (a0 != 1.f || a1 != 1.f || a2 != 1.f || a3 != 1.f) {
#pragma unroll
      for (int f = 0; f < 16; ++f) {
        o[f][0] *= a0; o[f][1] *= a1; o[f][2] *= a2; o[f][3] *= a3;
      }
    }
    const bf16x8 pa = *(const bf16x8*)((const char*)(&Pb[1][0]) +
                                       (r * 16 + l15) * 80 + (lq << 4));
    const char* vbase = (const char*)(&Vl[1][0]) + (lq << 13);
#pragma unroll
    for (int kk = 0; kk < 16; ++kk) {
      const int ci = (cg * 256 + kk * 16 + l15) ^ lq;
      const bf16x8 vf = *(const bf16x8*)(vbase + (ci << 4));
      o[kk] = __builtin_amdgcn_mfma_f32_16x16x32_bf16(pa, vf, o[kk], 0, 0, 0);
    }
  }
  {
    float li[4];
#pragma unroll
    for (int i = 0; i < 4; ++i) li[i] = 1.0f / lrow[rb + i];
    u16* ob = Oo + ((size_t)(b * 4096 + qb * 64)) * 512;
#pragma unroll
    for (int f = 0; f < 16; ++f) {
      const int col = cg * 256 + f * 16 + l15;
#pragma unroll
      for (int i = 0; i < 4; ++i)
        ob[(size_t)(rb + i) * 512 + col] = f2bf(o[f][i] * li[i]);
    }
  }
}

extern "C" void kernel_launch(void* const* d_in, const int* in_sizes, int n_in,
                              void* d_out, int out_size, void* d_ws, size_t ws_size,
                              hipStream_t stream) {
  const float* x     = (const float*)d_in[0];
  const float* gamma = (const float*)d_in[1];
  const float* beta  = (const float*)d_in[2];
  const float* wq    = (const float*)d_in[3];
  const float* bq    = (const float*)d_in[4];
  const float* wk    = (const float*)d_in[5];
  const float* bk    = (const float*)d_in[6];
  const float* wv    = (const float*)d_in[7];
  const float* bv    = (const float*)d_in[8];
  const float* wo    = (const float*)d_in[9];
  const float* bo    = (const float*)d_in[10];
  float* out = (float*)d_out;

  char* ws = (char*)d_ws;
  const size_t SZ = (size_t)16384 * 512;
  u16* h    = (u16*)(ws);                 // 16 MB
  u16* q    = (u16*)(ws + SZ * 2);        // 16 MB (pre-scaled by C^-0.5)
  u16* k    = (u16*)(ws + SZ * 4);        // 16 MB
  u16* v8   = (u16*)(ws + SZ * 6);        // 16 MB, [B][N/8][C^(blk&3)][8]
  u16* aout = (u16*)(ws + SZ * 8);        // 16 MB
  u16* wT   = (u16*)(ws + SZ * 10);       // 4 x 512KB
  float* part  = (float*)(ws + SZ * 10 + 4 * 262144 * 2);
  float* stats = part + 2048;

  gn_partial<<<dim3(8, 32, 4), 256, 0, stream>>>(x, part);
  gn_finalize<<<1, 128, 0, stream>>>(part, stats);
  gn_apply<<<8192, 256, 0, stream>>>(x, gamma, beta, stats, h);

  wcast_t4<<<4096, 256, 0, stream>>>(wq, wk, wv, wo, wT);

  const float qs = 0.044194173824159216f;  // 512^-0.5
  gemm_qkv<<<dim3(128, 12), 256, 0, stream>>>(h, wT, bq, bk, bv, q, k, v8, qs);

  attn_kernel<<<dim3(64, 4), 512, 0, stream>>>(q, k, v8, aout);

  gemm_oproj<<<dim3(128, 4), 256, 0, stream>>>(aout, wT + 3 * 262144, bo, x, out);
}